// Round 7
// baseline (244.725 us; speedup 1.0000x reference)
//
#include <hip/hip_runtime.h>
#include <hip/hip_bf16.h>

#define Bn 8
#define Nn 207
#define Tn 12
#define Cn 64
#define Ln (Nn*Tn)      // 2484
#define LP 2496         // padded to 64
#define NT 39           // LP/64
#define QDn 8
#define ES 2504         // e_s row stride (u16); 2504*2 % 16 == 0

typedef __hip_bfloat16 bf16;
typedef unsigned int u32;
typedef unsigned short u16;
typedef __attribute__((ext_vector_type(8))) short short8;
typedef __attribute__((ext_vector_type(4))) float floatx4;

__device__ __forceinline__ float lo2f(u32 u) { return __uint_as_float(u << 16); }
__device__ __forceinline__ float hi2f(u32 u) { return __uint_as_float(u & 0xFFFF0000u); }
__device__ __forceinline__ u16 f2bf(float f) { bf16 t = __float2bfloat16(f); return *(u16*)&t; }
__device__ __forceinline__ u32 pack2(float a, float b) { return ((u32)f2bf(b) << 16) | f2bf(a); }

// ---------------- ws layout (u16 offsets unless noted) ----------------
#define U_WA   0            // bf16 [3][8][64][8]  12288
#define U_WB   12288        // 12288 -> ends u16 24576 (byte 49152)
#define F_WQ   12288        // fp32 [c][8] 512 (float offsets)
#define F_WK   12800        // 512
#define F_WV   13312        // fp32 [c][o] 4096 -> ends float 17408 (byte 69632)
#define U_K    34816        // bf16 [Bn][LP][8]      159744 u16
#define U_HT   194560       // bf16 [Bn][NT][64][64] 1277952 u16 -> ends byte 2,945,024

__device__ __forceinline__ void unpack8(uint4 u, float* f) {
    f[0] = lo2f(u.x); f[1] = hi2f(u.x);
    f[2] = lo2f(u.y); f[3] = hi2f(u.y);
    f[4] = lo2f(u.z); f[5] = hi2f(u.z);
    f[6] = lo2f(u.w); f[7] = hi2f(u.w);
}

// ---------------- kernel 0: weight convert/transpose + k tail zero ----------
__global__ __launch_bounds__(256) void prep_kernel(
    const float* __restrict__ wA, const float* __restrict__ wB,
    const float* __restrict__ wq, const float* __restrict__ wk,
    const float* __restrict__ wv, float* __restrict__ ws)
{
    u16* wsu = (u16*)ws;
    int idx = blockIdx.x * 256 + threadIdx.x;
    if (idx < 12288) {
        int j = idx & 7, co = (idx >> 3) & 63, cig = (idx >> 9) & 7, k = idx >> 12;
        wsu[U_WA + idx] = f2bf(wA[(co*64 + cig*8 + j)*3 + k]);
    } else if (idx < 24576) {
        int i = idx - 12288;
        int j = i & 7, co = (i >> 3) & 63, cig = (i >> 9) & 7, k = i >> 12;
        wsu[U_WB + i] = f2bf(wB[(co*64 + cig*8 + j)*3 + k]);
    } else if (idx < 25088) {
        int j = idx - 24576; int o = j & 7, c = j >> 3;
        ws[F_WQ + j] = wq[o*Cn + c];
    } else if (idx < 25600) {
        int j = idx - 25088; int o = j & 7, c = j >> 3;
        ws[F_WK + j] = wk[o*Cn + c];
    } else if (idx < 29696) {
        int j = idx - 25600; int o = j & 63, c = j >> 6;
        ws[F_WV + j] = wv[o*Cn + c];
    } else if (idx < 30464) {
        int j = idx - 29696;            // k tail rows Ln..LP-1 (96 u16 per b)
        int b = j / 96, r = j - b*96;
        wsu[U_K + (size_t)b*LP*8 + Ln*8 + r] = 0;
    }
}

// ---------------- kernel 1: conv + GLU + k projection ----------------------
// one block per (b, n); h -> d_out fp32 (residual + transpose source); k -> ws bf16
__global__ __launch_bounds__(256) void conv_k_kernel(
    const float* __restrict__ X,
    const float* __restrict__ bA, const float* __restrict__ bB,
    const float* __restrict__ bk,
    float* __restrict__ ws, float* __restrict__ out)
{
    __shared__ float xs[Tn*Cn];
    __shared__ float hs[Tn*Cn];
    int b = blockIdx.x / Nn;
    int n = blockIdx.x % Nn;
    int tid = threadIdx.x;

    const float* Xp = X + (size_t)(b*Nn + n)*Tn*Cn;
    for (int i = tid; i < (Tn*Cn)/4; i += 256)
        ((float4*)xs)[i] = ((const float4*)Xp)[i];
    __syncthreads();

    int co = tid & 63;
    int tg = tid >> 6;                 // rows t = 3tg .. 3tg+2
    float aA[3] = {bA[co], bA[co], bA[co]};
    float aB[3] = {bB[co], bB[co], bB[co]};

    const u16* wap = (const u16*)ws + U_WA;
    const u16* wbp = (const u16*)ws + U_WB;
    int tb = tg*3 - 2;

    for (int cig = 0; cig < 8; ++cig) {
        float xr[5][8];
        #pragma unroll
        for (int d = 0; d < 5; ++d) {
            int tp = tb + d;
            if (tp >= 0) {
                float4 xa = *(const float4*)(xs + tp*Cn + cig*8);
                float4 xb = *(const float4*)(xs + tp*Cn + cig*8 + 4);
                xr[d][0]=xa.x; xr[d][1]=xa.y; xr[d][2]=xa.z; xr[d][3]=xa.w;
                xr[d][4]=xb.x; xr[d][5]=xb.y; xr[d][6]=xb.z; xr[d][7]=xb.w;
            } else {
                #pragma unroll
                for (int j = 0; j < 8; ++j) xr[d][j] = 0.f;
            }
        }
        #pragma unroll
        for (int k = 0; k < 3; ++k) {
            uint4 wau = *(const uint4*)(wap + ((k*8 + cig)*64 + co)*8);
            uint4 wbu = *(const uint4*)(wbp + ((k*8 + cig)*64 + co)*8);
            float wa8[8], wb8[8];
            unpack8(wau, wa8); unpack8(wbu, wb8);
            #pragma unroll
            for (int j = 0; j < 8; ++j) {
                #pragma unroll
                for (int tt = 0; tt < 3; ++tt) {
                    aA[tt] += xr[tt + k][j] * wa8[j];
                    aB[tt] += xr[tt + k][j] * wb8[j];
                }
            }
        }
    }

    #pragma unroll
    for (int tt = 0; tt < 3; ++tt) {
        int t = tg*3 + tt;
        float hv = aA[tt] * (1.f / (1.f + __expf(-aB[tt])));
        hs[t*Cn + co] = hv;
        out[((size_t)b*Ln + (size_t)n*Tn + t)*Cn + co] = hv;   // fp32 h
    }
    __syncthreads();

    // k projection: 12 rows x 8 outputs -> bf16
    if (tid < 96) {
        int r = tid >> 3, o = tid & 7;
        const float* wkt = ws + F_WK;
        float acc = bk[o];
        for (int c = 0; c < Cn; ++c) acc += hs[r*Cn + c] * wkt[c*QDn + o];
        u16* kw = (u16*)ws + U_K;
        kw[(size_t)b*LP*8 + ((size_t)n*Tn + r)*8 + o] = f2bf(acc);
    }
}

// ---------------- kernel 1b: h (fp32 [m][c]) -> hT (bf16 [tile][c][64m]) ----
// one block per (b, tile); coalesced row loads, in-register pack, uint4 stores
__global__ __launch_bounds__(256) void transpose_kernel(
    const float* __restrict__ out, float* __restrict__ ws)
{
    int b = blockIdx.x / NT;
    int t = blockIdx.x % NT;
    int m0 = t*64;
    int tid = threadIdx.x;
    int c = tid & 63;
    int mo = tid >> 6;                 // octs mo and mo+4

    u16* hT = (u16*)ws + U_HT + (size_t)b*NT*4096 + (size_t)t*4096;
    const float* hb = out + (size_t)b*Ln*Cn;

    #pragma unroll
    for (int oo = 0; oo < 2; ++oo) {
        int oct = mo + oo*4;
        float v[8];
        #pragma unroll
        for (int j = 0; j < 8; ++j) {
            int m = m0 + oct*8 + j;
            v[j] = (m < Ln) ? hb[(size_t)m*Cn + c] : 0.f;
        }
        uint4 p;
        p.x = pack2(v[0], v[1]); p.y = pack2(v[2], v[3]);
        p.z = pack2(v[4], v[5]); p.w = pack2(v[6], v[7]);
        *(uint4*)(hT + c*64 + oct*8) = p;
    }
}

// ---------------- kernel 2: attention, phase-split, barrier-free loops ------
__global__ __launch_bounds__(256) void attn_kernel(
    const float* __restrict__ gamma,
    const float* __restrict__ bq, const float* __restrict__ bv,
    const float* __restrict__ ws,
    float* __restrict__ out)
{
    __shared__ u16   e_s[12*ES];       // [r][m] bf16, full L
    __shared__ float hsf[Tn*Cn];
    __shared__ float ha_s[64*16];      // ha[c][r] (unnormalized)
    __shared__ float q_s[Tn*QDn];
    __shared__ float den_part[4*16];

    int b = blockIdx.x / Nn;
    int n = blockIdx.x % Nn;
    int tid = threadIdx.x;
    int lane = tid & 63;
    int wid = tid >> 6;                // wave w: m-strip 16w (ph1), c-strip 16w (ph2)
    int rm = lane & 15;
    int quad = lane >> 4;

    const float* hown = out + ((size_t)b*Ln + (size_t)n*Tn)*Cn;
    for (int i = tid; i < (Tn*Cn)/4; i += 256)
        ((float4*)hsf)[i] = ((const float4*)hown)[i];
    __syncthreads();

    // q (fp32) for own 12 rows
    if (tid < 96) {
        int r = tid >> 3, o = tid & 7;
        const float* wqt = ws + F_WQ;
        float acc = bq[o];
        for (int c = 0; c < Cn; ++c) acc += hsf[r*Cn + c] * wqt[c*QDn + o];
        q_s[r*QDn + o] = acc;
    }
    __syncthreads();

    // q B-frag: lane<12 holds q[r=lane][0..7]; other lanes zero (K-pad)
    uint4 qu = make_uint4(0, 0, 0, 0);
    if (lane < 12) {
        const float* qr = q_s + lane*QDn;
        qu.x = pack2(qr[0], qr[1]); qu.y = pack2(qr[2], qr[3]);
        qu.z = pack2(qr[4], qr[5]); qu.w = pack2(qr[6], qr[7]);
    }
    short8 qfrag = *(short8*)&qu;

    const u16* kb  = (const u16*)ws + U_K  + (size_t)b*LP*8;
    const u16* hTg = (const u16*)ws + U_HT + (size_t)b*NT*4096;

    // ================= phase 1: e for all tiles (no barriers) ===============
    float dsum = 0.f;
    {
        const u16* kwp = kb + (size_t)(16*wid + rm)*8;
        u16* erow = e_s + rm*ES + 16*wid + 4*quad;
        #pragma unroll
        for (int t = 0; t < NT; ++t) {
            int m0 = t*64;
            uint4 ku = make_uint4(0, 0, 0, 0);
            if (quad == 0) ku = *(const uint4*)(kwp + (size_t)m0*8);
            short8 kfrag = *(short8*)&ku;
            floatx4 sacc = {0.f, 0.f, 0.f, 0.f};
            sacc = __builtin_amdgcn_mfma_f32_16x16x32_bf16(kfrag, qfrag, sacc, 0, 0, 0);
            // lane holds s[m=m0+16w+4q+reg][r=rm]
            float e0, e1, e2, e3;
            if (t < NT-1) {
                e0 = __expf(sacc[0]); e1 = __expf(sacc[1]);
                e2 = __expf(sacc[2]); e3 = __expf(sacc[3]);
            } else {
                int mb = m0 + 16*wid + 4*quad;
                e0 = (mb+0 < Ln) ? __expf(sacc[0]) : 0.f;
                e1 = (mb+1 < Ln) ? __expf(sacc[1]) : 0.f;
                e2 = (mb+2 < Ln) ? __expf(sacc[2]) : 0.f;
                e3 = (mb+3 < Ln) ? __expf(sacc[3]) : 0.f;
            }
            dsum += e0 + e1 + e2 + e3;
            if (rm < 12)
                *(uint2*)(erow + m0) = make_uint2(pack2(e0, e1), pack2(e2, e3));
        }
    }
    // partial denominators (per wave = per m-strip)
    {
        float s_ = dsum;
        s_ += __shfl_xor(s_, 16, 64);
        s_ += __shfl_xor(s_, 32, 64);
        if (quad == 0) den_part[wid*16 + rm] = s_;
    }
    __syncthreads();

    // ================= phase 2: PV sweep (no barriers, pipelined) ===========
    floatx4 acc = {0.f, 0.f, 0.f, 0.f};
    {
        const u16* hrow = hTg + (size_t)(16*wid + rm)*64 + quad*8;
        int er = (rm < 12) ? rm : 11;       // rows 12..15 feed unused ha cols
        const u16* ep = e_s + er*ES + quad*8;
        #pragma unroll
        for (int t = 0; t < NT; ++t) {
            short8 a0 = *(const short8*)(hrow + (size_t)t*4096);
            short8 a1 = *(const short8*)(hrow + (size_t)t*4096 + 32);
            short8 b0 = *(const short8*)(ep + t*64);
            short8 b1 = *(const short8*)(ep + t*64 + 32);
            acc = __builtin_amdgcn_mfma_f32_16x16x32_bf16(a0, b0, acc, 0, 0, 0);
            acc = __builtin_amdgcn_mfma_f32_16x16x32_bf16(a1, b1, acc, 0, 0, 0);
        }
    }

    // D frags -> ha_s[c][r]
    int cl = 16*wid + quad*4;
    #pragma unroll
    for (int reg = 0; reg < 4; ++reg) ha_s[(cl + reg)*16 + rm] = acc[reg];
    __syncthreads();

    // ---- Wv projection + gamma residual ----
    float gam = gamma[0];
    const float* wvt = ws + F_WV;
    int o = lane;
    float bvo = bv[o];
    #pragma unroll
    for (int rr = 0; rr < 3; ++rr) {
        int r = wid*3 + rr;
        float den = den_part[r] + den_part[16 + r] + den_part[32 + r] + den_part[48 + r];
        float inv = 1.f / den;
        float p = 0.f;
        #pragma unroll 8
        for (int c = 0; c < Cn; ++c) p += wvt[c*Cn + o] * ha_s[c*16 + r];
        out[((size_t)b*Ln + (size_t)n*Tn + r)*Cn + o] = gam*(bvo + inv*p) + hsf[r*Cn + o];
    }
}

// ---------------- launch ----------------
extern "C" void kernel_launch(void* const* d_in, const int* in_sizes, int n_in,
                              void* d_out, int out_size, void* d_ws, size_t ws_size,
                              hipStream_t stream) {
    const float* X     = (const float*)d_in[0];
    const float* wA    = (const float*)d_in[1];
    const float* bA    = (const float*)d_in[2];
    const float* wB    = (const float*)d_in[3];
    const float* bB    = (const float*)d_in[4];
    const float* wq    = (const float*)d_in[5];
    const float* bq    = (const float*)d_in[6];
    const float* wk    = (const float*)d_in[7];
    const float* bk    = (const float*)d_in[8];
    const float* wv    = (const float*)d_in[9];
    const float* bv    = (const float*)d_in[10];
    const float* gamma = (const float*)d_in[11];
    float* out = (float*)d_out;
    float* ws  = (float*)d_ws;

    prep_kernel<<<119, 256, 0, stream>>>(wA, wB, wq, wk, wv, ws);
    conv_k_kernel<<<Bn*Nn, 256, 0, stream>>>(X, bA, bB, bk, ws, out);
    transpose_kernel<<<Bn*NT, 256, 0, stream>>>(out, ws);
    attn_kernel<<<Bn*Nn, 256, 0, stream>>>(gamma, bq, bv, ws, out);
}

// Round 8
// 193.595 us; speedup vs baseline: 1.2641x; 1.2641x over previous
//
#include <hip/hip_runtime.h>
#include <hip/hip_bf16.h>

#define Bn 8
#define Nn 207
#define Tn 12
#define Cn 64
#define Ln (Nn*Tn)      // 2484
#define LP 2496         // padded to 64
#define NT 39           // LP/64
#define NB 104          // n-pair blocks per batch (2 n's = 24 rows each)

typedef unsigned int u32;
typedef unsigned short u16;
typedef _Float16 f16;
typedef __attribute__((ext_vector_type(4))) _Float16 half4;
typedef __attribute__((ext_vector_type(4))) float floatx4;

__device__ __forceinline__ u16 f2h(float f) { f16 h = (f16)f; return *(u16*)&h; }

// ---------------- ws layout ----------------
// u16 offsets:
#define U_WA   0            // f16 [k][cig][co][8]  12288
#define U_WB   12288        // 12288 -> 24576
#define U_WVT  24576        // f16 [o][c] 4096 -> 28672
// float offsets:
#define F_WK   14336        // fp32 [c][8] 512   (u16 28672..29696)
#define F_WQ   14848        // fp32 [c][8] 512   (ends float 15360 = u16 30720)
// u16 offsets:
#define U_K    30720        // f16 [Bn][LP][8]        159744 -> 190464
#define U_Q    190464       // f16 [Bn][LP][8]        159744 -> 350208
#define U_HT   350208       // f16 [Bn][NT][64][64]  1277952 -> 1628160 (3.26 MB)

// ---------------- kernel 0: weight convert + pad zeroing ----------
__global__ __launch_bounds__(256) void prep_kernel(
    const float* __restrict__ wA, const float* __restrict__ wB,
    const float* __restrict__ wq, const float* __restrict__ wk,
    const float* __restrict__ wv, float* __restrict__ ws)
{
    u16* wsu = (u16*)ws;
    int idx = blockIdx.x * 256 + threadIdx.x;
    if (idx < 12288) {
        int j = idx & 7, co = (idx >> 3) & 63, cig = (idx >> 9) & 7, k = idx >> 12;
        wsu[U_WA + idx] = f2h(wA[(co*64 + cig*8 + j)*3 + k]);
    } else if (idx < 24576) {
        int i = idx - 12288;
        int j = i & 7, co = (i >> 3) & 63, cig = (i >> 9) & 7, k = i >> 12;
        wsu[U_WB + i] = f2h(wB[(co*64 + cig*8 + j)*3 + k]);
    } else if (idx < 28672) {
        int j = idx - 24576;            // wvT[o][c] = wv[o][c] straight cast
        wsu[U_WVT + j] = f2h(wv[j]);
    } else if (idx < 29184) {
        int j = idx - 28672; int o = j & 7, c = j >> 3;
        ws[F_WK + j] = wk[o*Cn + c];
    } else if (idx < 29696) {
        int j = idx - 29184; int o = j & 7, c = j >> 3;
        ws[F_WQ + j] = wq[o*Cn + c];
    } else if (idx < 31232) {
        int j = idx - 29696;            // zero k/q pad rows Ln..LP-1
        int b = j / 192, rem = j - b*192;
        int which = rem / 96, rr = rem - which*96;
        wsu[(which ? U_Q : U_K) + (size_t)b*LP*8 + Ln*8 + rr] = 0;
    } else if (idx < 37376) {
        int j = idx - 31232;            // zero hT tail: tile 38, m-local 52..63
        int b = j / 768, rem = j - b*768;
        int c = rem / 12, mm = 52 + (rem - c*12);
        wsu[U_HT + (size_t)b*NT*4096 + (size_t)(NT-1)*4096 + c*64 + mm] = 0;
    }
}

// ---------------- kernel 1: conv + GLU + k/q proj + hT transpose -----------
// one block per (b, n); h -> d_out fp32; k,q,hT -> ws f16
__global__ __launch_bounds__(256) void conv_k_kernel(
    const float* __restrict__ X,
    const float* __restrict__ bA, const float* __restrict__ bB,
    const float* __restrict__ bk, const float* __restrict__ bq,
    float* __restrict__ ws, float* __restrict__ out)
{
    __shared__ float xs[Tn*Cn];
    __shared__ float hs[Tn*Cn];
    __shared__ float wkq_s[1024];      // wk[c][8] then wq[c][8]
    int b = blockIdx.x / Nn;
    int n = blockIdx.x % Nn;
    int tid = threadIdx.x;

    const float* Xp = X + (size_t)(b*Nn + n)*Tn*Cn;
    for (int i = tid; i < (Tn*Cn)/4; i += 256)
        ((float4*)xs)[i] = ((const float4*)Xp)[i];
    ((float4*)wkq_s)[tid] = ((const float4*)(ws + F_WK))[tid];
    __syncthreads();

    int co = tid & 63;
    int tg = tid >> 6;                 // rows t = 3tg .. 3tg+2
    float aA[3] = {bA[co], bA[co], bA[co]};
    float aB[3] = {bB[co], bB[co], bB[co]};

    const u16* wap = (const u16*)ws + U_WA;
    const u16* wbp = (const u16*)ws + U_WB;
    int tb = tg*3 - 2;

    for (int cig = 0; cig < 8; ++cig) {
        float xr[5][8];
        #pragma unroll
        for (int d = 0; d < 5; ++d) {
            int tp = tb + d;
            if (tp >= 0) {
                float4 xa = *(const float4*)(xs + tp*Cn + cig*8);
                float4 xb = *(const float4*)(xs + tp*Cn + cig*8 + 4);
                xr[d][0]=xa.x; xr[d][1]=xa.y; xr[d][2]=xa.z; xr[d][3]=xa.w;
                xr[d][4]=xb.x; xr[d][5]=xb.y; xr[d][6]=xb.z; xr[d][7]=xb.w;
            } else {
                #pragma unroll
                for (int j = 0; j < 8; ++j) xr[d][j] = 0.f;
            }
        }
        #pragma unroll
        for (int k = 0; k < 3; ++k) {
            uint4 wau = *(const uint4*)(wap + ((k*8 + cig)*64 + co)*8);
            uint4 wbu = *(const uint4*)(wbp + ((k*8 + cig)*64 + co)*8);
            const f16* wa8 = (const f16*)&wau;
            const f16* wb8 = (const f16*)&wbu;
            #pragma unroll
            for (int j = 0; j < 8; ++j) {
                float wa = (float)wa8[j], wb = (float)wb8[j];
                #pragma unroll
                for (int tt = 0; tt < 3; ++tt) {
                    aA[tt] += xr[tt + k][j] * wa;
                    aB[tt] += xr[tt + k][j] * wb;
                }
            }
        }
    }

    #pragma unroll
    for (int tt = 0; tt < 3; ++tt) {
        int t = tg*3 + tt;
        float hv = aA[tt] * (1.f / (1.f + __expf(-aB[tt])));
        hs[t*Cn + co] = hv;
        out[((size_t)b*Ln + (size_t)n*Tn + t)*Cn + co] = hv;   // fp32 h
    }
    __syncthreads();

    // k/q projections (threads 0..95 / 96..191) + hT transpose (0..191)
    if (tid < 96) {
        int r = tid >> 3, o = tid & 7;
        float acc = bk[o];
        for (int c = 0; c < Cn; ++c) acc += hs[r*Cn + c] * wkq_s[c*8 + o];
        ((u16*)ws)[U_K + (size_t)b*LP*8 + ((size_t)n*Tn + r)*8 + o] = f2h(acc);
    } else if (tid < 192) {
        int r = (tid - 96) >> 3, o = tid & 7;
        float acc = bq[o];
        for (int c = 0; c < Cn; ++c) acc += hs[r*Cn + c] * wkq_s[512 + c*8 + o];
        ((u16*)ws)[U_Q + (size_t)b*LP*8 + ((size_t)n*Tn + r)*8 + o] = f2h(acc);
    }
    {
        int j = tid >> 6, c = tid & 63;
        if (j < 3) {
            int m = n*Tn + 4*j;        // 4-aligned, never crosses a 64-tile
            u32 p0 = ((u32)f2h(hs[(4*j+1)*Cn + c]) << 16) | f2h(hs[(4*j+0)*Cn + c]);
            u32 p1 = ((u32)f2h(hs[(4*j+3)*Cn + c]) << 16) | f2h(hs[(4*j+2)*Cn + c]);
            u16* ht = (u16*)ws + U_HT + (size_t)b*NT*4096 + (size_t)(m >> 6)*4096 + c*64 + (m & 63);
            *(uint2*)ht = make_uint2(p0, p1);
        }
    }
}

// ---------------- kernel 2: register-fused flash attention -----------------
// one block per (b, n-pair): 24 rows. K=16 MFMAs; QK C-layout == PV B-layout
// -> e stays in registers, zero barriers in main loop.
__global__ __launch_bounds__(256) void attn_kernel(
    const float* __restrict__ gamma, const float* __restrict__ bv,
    const float* __restrict__ ws, float* __restrict__ out)
{
    __shared__ float part[4*64*24];    // [w][c][r] partial ha
    __shared__ float den_part[4][32];

    int b  = blockIdx.x / NB;
    int nb = blockIdx.x % NB;
    int R0 = nb*24;
    int tid = threadIdx.x;
    int lane = tid & 63;
    int w = tid >> 6;
    int rm = lane & 15;
    int quad = lane >> 4;

    const u16* wsu = (const u16*)ws;
    const u16* kb = wsu + U_K  + (size_t)b*LP*8;
    const u16* qb = wsu + U_Q  + (size_t)b*LP*8;
    const u16* hb = wsu + U_HT + (size_t)b*NT*4096;

    // q B-frags for the 2 row-groups (load once; d-pad quads 2,3 = 0)
    half4 qf[2];
    #pragma unroll
    for (int g = 0; g < 2; ++g) {
        uint2 u = make_uint2(0, 0);
        int row = R0 + g*16 + rm;
        if (row >= LP) row = LP - 1;   // clamped rows are zero-pad / unused
        if (quad < 2) u = *(const uint2*)(qb + (size_t)row*8 + 4*quad);
        qf[g] = *(half4*)&u;
    }

    floatx4 acc[4][2];
    #pragma unroll
    for (int cs = 0; cs < 4; ++cs)
        #pragma unroll
        for (int g = 0; g < 2; ++g) acc[cs][g] = (floatx4){0.f, 0.f, 0.f, 0.f};
    float dsum[2] = {0.f, 0.f};

    for (int tt = 0; tt < 10; ++tt) {
        int t = tt*4 + w;              // wave w owns whole 64-m tiles t ≡ w (mod 4)
        if (t >= NT) break;
        const u16* kt = kb + (size_t)t*512;
        const u16* ht = hb + (size_t)t*4096;
        bool tail = (t == NT-1);
        #pragma unroll
        for (int ss = 0; ss < 4; ++ss) {
            // QK: A = k rows [m][d] (quads 0,1 real)
            uint2 ku = make_uint2(0, 0);
            if (quad < 2) ku = *(const uint2*)(kt + (ss*16 + rm)*8 + 4*quad);
            half4 kf = *(half4*)&ku;
            floatx4 s0 = {0.f,0.f,0.f,0.f}, s1 = {0.f,0.f,0.f,0.f};
            s0 = __builtin_amdgcn_mfma_f32_16x16x16f16(kf, qf[0], s0, 0, 0, 0);
            s1 = __builtin_amdgcn_mfma_f32_16x16x16f16(kf, qf[1], s1, 0, 0, 0);
            // e: lane(quad,rm) reg i holds e[m=m0+4q+i][r=rm] == PV B-frag layout
            half4 e0, e1;
            int mb = t*64 + ss*16 + 4*quad;
            #pragma unroll
            for (int i = 0; i < 4; ++i) {
                float ev0 = __expf(s0[i]);
                float ev1 = __expf(s1[i]);
                if (tail && (mb + i >= Ln)) { ev0 = 0.f; ev1 = 0.f; }
                dsum[0] += ev0; dsum[1] += ev1;
                e0[i] = (f16)ev0; e1[i] = (f16)ev1;
            }
            // PV: A = hT[c][m] per c-strip; same e frags for both row-groups
            #pragma unroll
            for (int cs = 0; cs < 4; ++cs) {
                uint2 au = *(const uint2*)(ht + (cs*16 + rm)*64 + ss*16 + 4*quad);
                half4 af = *(half4*)&au;
                acc[cs][0] = __builtin_amdgcn_mfma_f32_16x16x16f16(af, e0, acc[cs][0], 0, 0, 0);
                acc[cs][1] = __builtin_amdgcn_mfma_f32_16x16x16f16(af, e1, acc[cs][1], 0, 0, 0);
            }
        }
    }

    // denominator partials: sum quads sharing r
    #pragma unroll
    for (int g = 0; g < 2; ++g) {
        float s_ = dsum[g];
        s_ += __shfl_xor(s_, 16, 64);
        s_ += __shfl_xor(s_, 32, 64);
        if (quad == 0) den_part[w][g*16 + rm] = s_;
    }

    // write partial ha: D[c_local=4*quad+reg][r=rm]
    float* pw = part + w*1536;
    #pragma unroll
    for (int cs = 0; cs < 4; ++cs)
        #pragma unroll
        for (int g = 0; g < 2; ++g) {
            if (g == 0 || rm < 8) {
                int r = g*16 + rm;
                #pragma unroll
                for (int i = 0; i < 4; ++i)
                    pw[(cs*16 + quad*4 + i)*24 + r] = acc[cs][g][i];
            }
        }
    __syncthreads();

    // reduce 4 wave-partials
    for (int j = tid; j < 1536; j += 256)
        part[j] = part[j] + part[1536 + j] + part[3072 + j] + part[4608 + j];
    __syncthreads();

    // epilogue: Wv (f16 rows) + gamma residual
    int o = tid & 63, rq = tid >> 6;
    float gam = gamma[0];
    float bvo = bv[o];
    const u16* wvr = wsu + U_WVT + o*64;
    uint4 wvu[8];
    #pragma unroll
    for (int x = 0; x < 8; ++x) wvu[x] = *(const uint4*)(wvr + x*8);
    #pragma unroll
    for (int rr = 0; rr < 6; ++rr) {
        int r = rq*6 + rr;
        int row = R0 + r;
        if (row < Ln) {
            float den = den_part[0][r] + den_part[1][r] + den_part[2][r] + den_part[3][r];
            float p = 0.f;
            #pragma unroll
            for (int x = 0; x < 8; ++x) {
                const f16* hh = (const f16*)&wvu[x];
                #pragma unroll
                for (int i = 0; i < 8; ++i)
                    p += (float)hh[i] * part[(x*8 + i)*24 + r];
            }
            size_t gi = ((size_t)b*Ln + row)*64 + o;
            out[gi] = gam*(bvo + p/den) + out[gi];
        }
    }
}

// ---------------- launch ----------------
extern "C" void kernel_launch(void* const* d_in, const int* in_sizes, int n_in,
                              void* d_out, int out_size, void* d_ws, size_t ws_size,
                              hipStream_t stream) {
    const float* X     = (const float*)d_in[0];
    const float* wA    = (const float*)d_in[1];
    const float* bA    = (const float*)d_in[2];
    const float* wB    = (const float*)d_in[3];
    const float* bB    = (const float*)d_in[4];
    const float* wq    = (const float*)d_in[5];
    const float* bq    = (const float*)d_in[6];
    const float* wk    = (const float*)d_in[7];
    const float* bk    = (const float*)d_in[8];
    const float* wv    = (const float*)d_in[9];
    const float* bv    = (const float*)d_in[10];
    const float* gamma = (const float*)d_in[11];
    float* out = (float*)d_out;
    float* ws  = (float*)d_ws;

    prep_kernel<<<146, 256, 0, stream>>>(wA, wB, wq, wk, wv, ws);
    conv_k_kernel<<<Bn*Nn, 256, 0, stream>>>(X, bA, bB, bk, bq, ws, out);
    attn_kernel<<<Bn*NB, 256, 0, stream>>>(gamma, bv, ws, out);
}